// Round 6
// baseline (8140.175 us; speedup 1.0000x reference)
//
#include <hip/hip_runtime.h>
#include <math.h>

// Problem constants (match reference)
#define NN 50000
#define SEQ 52
#define FIN 16
#define HD 128
#define NEG_SLOPE 0.2f

typedef short bf16x8 __attribute__((ext_vector_type(8)));   // 8 bf16 (4 VGPRs)
typedef float f32x16 __attribute__((ext_vector_type(16)));  // 32x32 MFMA C/D

__device__ __forceinline__ short f2bf(float x) {
    unsigned u = __float_as_uint(x);
    u += 0x7fffu + ((u >> 16) & 1u);   // round-to-nearest-even
    return (short)(u >> 16);
}
__device__ __forceinline__ float b2f(short s) {
    return __uint_as_float(((unsigned)(unsigned short)s) << 16);
}

// ---------------------------------------------------------------------------
// CSR build kernels (run once per launch; graph is static across timesteps)
// ---------------------------------------------------------------------------
__global__ void deg_init_kernel(int* deg, int n) {
    int i = blockIdx.x * blockDim.x + threadIdx.x;
    if (i < n) deg[i] = 1;  // self-loop
}

__global__ void deg_count_kernel(const int* __restrict__ dst, int* deg, int e) {
    int i = blockIdx.x * blockDim.x + threadIdx.x;
    if (i < e) atomicAdd(&deg[dst[i]], 1);
}

__global__ __launch_bounds__(1024) void scan_kernel(const int* __restrict__ deg,
                                                    int* row_ptr, int n) {
    __shared__ int buf[1024];
    __shared__ int carry;
    int tid = threadIdx.x;
    if (tid == 0) carry = 0;
    __syncthreads();
    for (int base = 0; base < n; base += 1024) {
        int i = base + tid;
        int v = (i < n) ? deg[i] : 0;
        buf[tid] = v;
        __syncthreads();
        for (int off = 1; off < 1024; off <<= 1) {
            int t = (tid >= off) ? buf[tid - off] : 0;
            __syncthreads();
            buf[tid] += t;
            __syncthreads();
        }
        if (i < n) row_ptr[i] = carry + buf[tid] - v;  // exclusive
        __syncthreads();
        if (tid == 1023) carry += buf[1023];
        __syncthreads();
    }
    if (tid == 0) row_ptr[n] = carry;
}

__global__ void selfloop_kernel(const int* __restrict__ row_ptr, int* cursor,
                                int* col, int n) {
    int i = blockIdx.x * blockDim.x + threadIdx.x;
    if (i < n) {
        int p = row_ptr[i];
        col[p] = i;          // self-loop first
        cursor[i] = p + 1;
    }
}

__global__ void scatter_kernel(const int* __restrict__ src, const int* __restrict__ dst,
                               int* cursor, int* col, int e) {
    int i = blockIdx.x * blockDim.x + threadIdx.x;
    if (i < e) {
        int p = atomicAdd(&cursor[dst[i]], 1);
        col[p] = src[i];
    }
}

// ---------------------------------------------------------------------------
// Pack W_ih/W_hh into MFMA B-fragment order, split bf16 hi/lo.
// Index: ((((g*4+slab)*8+ks)*4+which)*64+lane)*8 shorts,
//   which: 0=ih_hi 1=ih_lo 2=hh_hi 3=hh_lo
//   col = slab*32 + (lane&31), kcol = ks*16 + (lane>>5)*8
// In the GRU K-loop every weight load is lane-contiguous 16B -> coalesced.
// ---------------------------------------------------------------------------
__global__ void wpack_kernel(const float* __restrict__ Wi, const float* __restrict__ Wh,
                             short* __restrict__ wfrag) {
    int idx = blockIdx.x * blockDim.x + threadIdx.x;
    if (idx >= 3 * 4 * 8 * 4 * 64) return;
    int lane = idx & 63;
    int which = (idx >> 6) & 3;
    int ks = (idx >> 8) & 7;
    int slab = (idx >> 11) & 3;
    int g = idx >> 13;
    int col = slab * 32 + (lane & 31);
    int kcol = ks * 16 + (lane >> 5) * 8;
    const float* Wsrc = (which < 2) ? Wi : Wh;
    const float* row = Wsrc + (size_t)(g * HD + col) * HD + kcol;
    short* dstp = wfrag + (size_t)idx * 8;
    bool lo = (which & 1);
#pragma unroll
    for (int e = 0; e < 8; ++e) {
        float v = row[e];
        short hi = f2bf(v);
        dstp[e] = lo ? f2bf(v - b2f(hi)) : hi;
    }
}

// ---------------------------------------------------------------------------
// Per-timestep kernels
// ---------------------------------------------------------------------------

// xp = x_t @ Wg (stored bf16); a_s = xp.att_src ; a_d = xp.att_dst (fp32 pre-round)
// One wave per node; lane handles features 2*lane, 2*lane+1 -> one packed u32 store.
__global__ __launch_bounds__(256) void xp_kernel(
    const float* __restrict__ x, const float* __restrict__ Wg,
    const float* __restrict__ att_src, const float* __restrict__ att_dst,
    unsigned* __restrict__ xpb, float* __restrict__ a_s, float* __restrict__ a_d, int n) {
    int wave = (blockIdx.x * blockDim.x + threadIdx.x) >> 6;
    int lane = threadIdx.x & 63;
    if (wave >= n) return;
    const float* xr = x + (size_t)wave * FIN;
    float xv[FIN];
#pragma unroll
    for (int k = 0; k < FIN; ++k) xv[k] = xr[k];
    int c0 = 2 * lane, c1 = 2 * lane + 1;
    float v0 = 0.f, v1 = 0.f;
#pragma unroll
    for (int k = 0; k < FIN; ++k) {
        v0 += xv[k] * Wg[k * HD + c0];
        v1 += xv[k] * Wg[k * HD + c1];
    }
    unsigned p = (unsigned)(unsigned short)f2bf(v0) |
                 ((unsigned)(unsigned short)f2bf(v1) << 16);
    xpb[(size_t)wave * 64 + lane] = p;
    float s = v0 * att_src[c0] + v1 * att_src[c1];
    float d = v0 * att_dst[c0] + v1 * att_dst[c1];
#pragma unroll
    for (int off = 32; off; off >>= 1) {
        s += __shfl_xor(s, off);
        d += __shfl_xor(d, off);
    }
    if (lane == 0) { a_s[wave] = s; a_d[wave] = d; }
}

// GAT softmax-aggregate: one wave per dst node, bf16 xp rows (256B/edge).
// Single pass (no max subtraction: scores ~N(0,0.64), exp() is safe).
// Lanes = 4 edge-groups x 16 feature-lanes; lane reads bf16x8 (16B) per edge.
__global__ __launch_bounds__(256) void gat_kernel(
    const int* __restrict__ row_ptr, const int* __restrict__ col,
    const float* __restrict__ a_s, const float* __restrict__ a_d,
    const short* __restrict__ xpb, const float* __restrict__ bias_g,
    float* __restrict__ spatial, int n) {
    int wave = (blockIdx.x * blockDim.x + threadIdx.x) >> 6;
    int lane = threadIdx.x & 63;
    if (wave >= n) return;
    int start = row_ptr[wave], end = row_ptr[wave + 1];
    int eg = lane >> 4;   // edge group 0..3
    int fg = lane & 15;   // feature lane 0..15 (features fg*8..fg*8+7)
    float ad = a_d[wave];
    float acc[8] = {0.f, 0.f, 0.f, 0.f, 0.f, 0.f, 0.f, 0.f};
    float denom = 0.f;
    for (int i = start + eg; i < end; i += 4) {
        int s = col[i];
        float e = a_s[s] + ad;
        e = (e > 0.f) ? e : NEG_SLOPE * e;
        float wgt = __expf(e);
        denom += wgt;
        bf16x8 row = *(const bf16x8*)(xpb + (size_t)s * HD + fg * 8);
#pragma unroll
        for (int j = 0; j < 8; ++j) acc[j] += wgt * b2f(row[j]);
    }
    // reduce across the 4 edge groups (lane bits 4,5)
    denom += __shfl_xor(denom, 16);
    denom += __shfl_xor(denom, 32);
#pragma unroll
    for (int j = 0; j < 8; ++j) {
        acc[j] += __shfl_xor(acc[j], 16);
        acc[j] += __shfl_xor(acc[j], 32);
    }
    float inv = 1.f / denom;
    // each lane writes 2 of its 8 features: f = fg*8 + eg*2 + jj
#pragma unroll
    for (int jj = 0; jj < 2; ++jj) {
        int f = fg * 8 + eg * 2 + jj;
        float o = acc[eg * 2 + jj] * inv + bias_g[f];
        spatial[(size_t)wave * HD + f] = fmaxf(o, 0.f);
    }
}

// ---------------------------------------------------------------------------
// MFMA GRU, 64-node tile: 2 node-tiles per wave share one weight stream.
//   gi = spatial @ W_ih^T, gh = h @ W_hh^T via v_mfma_f32_32x32x16_bf16
//   split-bf16: A*W ~= Ah*Wh + Al*Wh + Ah*Wl (fp32 accumulate)
// Weight traffic: 384KB per 64 nodes (was per 32) -> 300 MB/step L2 floor 8.7us.
// Each 12-load prefetch burst is covered by 36 MFMAs (288 cyc) -> single wave
// self-hides L2 latency; launch_bounds(256,1) accepts 1 wave/SIMD (~340 regs).
// ---------------------------------------------------------------------------
__global__ __launch_bounds__(256, 1) void gru_mfma_kernel(
    const float* __restrict__ spatial, float* __restrict__ h,
    const short* __restrict__ wfrag,
    const float* __restrict__ b_ih, const float* __restrict__ b_hh, int n) {
    // A-frag LDS: [tile*512 + ks*64 + lane], 2 tiles of 32 nodes
    __shared__ bf16x8 sSH[1024];  // spatial hi
    __shared__ bf16x8 sSL[1024];  // spatial lo
    __shared__ bf16x8 sHH[1024];  // h hi
    __shared__ bf16x8 sHL[1024];  // h lo

    int t = threadIdx.x;
    int lane = t & 63;
    int w = t >> 6;
    int n0 = blockIdx.x * 64;

    // ---- stage: wave w converts ks 2w,2w+1 for both tiles ----
#pragma unroll
    for (int q = 0; q < 4; ++q) {
        int tile = q >> 1;
        int ks = w * 2 + (q & 1);
        int row = n0 + tile * 32 + (lane & 31);
        if (row >= n) row = n - 1;
        int kcol = ks * 16 + (lane >> 5) * 8;
        const float* sp = spatial + (size_t)row * HD + kcol;
        const float* hp = h + (size_t)row * HD + kcol;
        float s8[8], h8[8];
        *(float4*)(s8) = *(const float4*)(sp);
        *(float4*)(s8 + 4) = *(const float4*)(sp + 4);
        *(float4*)(h8) = *(const float4*)(hp);
        *(float4*)(h8 + 4) = *(const float4*)(hp + 4);
        bf16x8 sh, sl, hh, hl;
#pragma unroll
        for (int j = 0; j < 8; ++j) {
            short a = f2bf(s8[j]);
            sh[j] = a;
            sl[j] = f2bf(s8[j] - b2f(a));
            short b = f2bf(h8[j]);
            hh[j] = b;
            hl[j] = f2bf(h8[j] - b2f(b));
        }
        int li = tile * 512 + ks * 64 + lane;
        sSH[li] = sh; sSL[li] = sl; sHH[li] = hh; sHL[li] = hl;
    }
    __syncthreads();

    int j0 = w * 32;
    int cj = lane & 31;       // column within wave's 32-col slab
    int kh = lane >> 5;       // k-half for frags

    f32x16 ai[2][3], ah[2][3];
#pragma unroll
    for (int tile = 0; tile < 2; ++tile)
#pragma unroll
        for (int g = 0; g < 3; ++g)
#pragma unroll
            for (int r = 0; r < 16; ++r) { ai[tile][g][r] = 0.f; ah[tile][g][r] = 0.f; }

    // fragment-ordered weight base for this wave: + g*65536 + ks*2048 + which*512
    const short* wb = wfrag + (size_t)w * 16384 + (size_t)lane * 8;

    // weight double buffer: [buf][g*4 + which]
    bf16x8 wv[2][12];
#pragma unroll
    for (int g = 0; g < 3; ++g) {
#pragma unroll
        for (int q = 0; q < 4; ++q)
            wv[0][g * 4 + q] = *(const bf16x8*)(wb + g * 65536 + q * 512);
    }

#pragma unroll
    for (int ks = 0; ks < 8; ++ks) {
        int cur = ks & 1;
        if (ks < 7) {
            int nxt = cur ^ 1;
#pragma unroll
            for (int g = 0; g < 3; ++g) {
#pragma unroll
                for (int q = 0; q < 4; ++q)
                    wv[nxt][g * 4 + q] =
                        *(const bf16x8*)(wb + g * 65536 + (ks + 1) * 2048 + q * 512);
            }
        }
#pragma unroll
        for (int tile = 0; tile < 2; ++tile) {
            int li = tile * 512 + ks * 64 + lane;
            bf16x8 aSH = sSH[li];
            bf16x8 aSL = sSL[li];
            bf16x8 aHH = sHH[li];
            bf16x8 aHL = sHL[li];
#pragma unroll
            for (int g = 0; g < 3; ++g) {
                bf16x8 wih = wv[cur][g * 4 + 0];
                bf16x8 wil = wv[cur][g * 4 + 1];
                bf16x8 whh = wv[cur][g * 4 + 2];
                bf16x8 whl = wv[cur][g * 4 + 3];
                ai[tile][g] = __builtin_amdgcn_mfma_f32_32x32x16_bf16(aSH, wih, ai[tile][g], 0, 0, 0);
                ah[tile][g] = __builtin_amdgcn_mfma_f32_32x32x16_bf16(aHH, whh, ah[tile][g], 0, 0, 0);
                ai[tile][g] = __builtin_amdgcn_mfma_f32_32x32x16_bf16(aSL, wih, ai[tile][g], 0, 0, 0);
                ah[tile][g] = __builtin_amdgcn_mfma_f32_32x32x16_bf16(aHL, whh, ah[tile][g], 0, 0, 0);
                ai[tile][g] = __builtin_amdgcn_mfma_f32_32x32x16_bf16(aSH, wil, ai[tile][g], 0, 0, 0);
                ah[tile][g] = __builtin_amdgcn_mfma_f32_32x32x16_bf16(aHH, whl, ah[tile][g], 0, 0, 0);
            }
        }
    }

    // ---- wave-local GRU elementwise + h write (both tiles) ----
    int j = j0 + cj;
    float bir = b_ih[j],        bhr = b_hh[j];
    float biz = b_ih[HD + j],   bhz = b_hh[HD + j];
    float bin_ = b_ih[2 * HD + j], bhn = b_hh[2 * HD + j];
    const short* hhs = (const short*)sHH;
    const short* hls = (const short*)sHL;
    int ksj = j >> 4, halfj = (j >> 3) & 1, ej = j & 7;

#pragma unroll
    for (int tile = 0; tile < 2; ++tile) {
#pragma unroll
        for (int r = 0; r < 16; ++r) {
            int nl = (r & 3) + 8 * (r >> 2) + 4 * kh;  // C/D row mapping (m74/m101)
            int node = n0 + tile * 32 + nl;
            if (node < n) {
                float gir = ai[tile][0][r] + bir, giz = ai[tile][1][r] + biz,
                      gin = ai[tile][2][r] + bin_;
                float ghr = ah[tile][0][r] + bhr, ghz = ah[tile][1][r] + bhz,
                      ghn = ah[tile][2][r] + bhn;
                float rr = 1.f / (1.f + __expf(-(gir + ghr)));
                float zz = 1.f / (1.f + __expf(-(giz + ghz)));
                float nn2 = tanhf(gin + rr * ghn);
                int li = (tile * 512 + ksj * 64 + nl + 32 * halfj) * 8 + ej;
                float hold = b2f(hhs[li]) + b2f(hls[li]);
                h[(size_t)node * HD + j] = (1.f - zz) * nn2 + zz * hold;
            }
        }
    }
}

// out[n] = h[n] . W_fc + b_fc   (one wave per node)
__global__ __launch_bounds__(256) void fc_kernel(
    const float* __restrict__ h, const float* __restrict__ W_fc,
    const float* __restrict__ b_fc, float* __restrict__ out, int n) {
    int wave = (blockIdx.x * blockDim.x + threadIdx.x) >> 6;
    int lane = threadIdx.x & 63;
    if (wave >= n) return;
    float v = h[(size_t)wave * HD + lane] * W_fc[lane] +
              h[(size_t)wave * HD + lane + 64] * W_fc[lane + 64];
#pragma unroll
    for (int off = 32; off; off >>= 1) v += __shfl_xor(v, off);
    if (lane == 0) out[wave] = v + b_fc[0];
}

// ---------------------------------------------------------------------------
extern "C" void kernel_launch(void* const* d_in, const int* in_sizes, int n_in,
                              void* d_out, int out_size, void* d_ws, size_t ws_size,
                              hipStream_t stream) {
    const float* x_seq   = (const float*)d_in[0];
    const int*   ei      = (const int*)d_in[1];
    const float* Wg      = (const float*)d_in[2];
    const float* att_src = (const float*)d_in[3];
    const float* att_dst = (const float*)d_in[4];
    const float* bias_g  = (const float*)d_in[5];
    const float* W_ih    = (const float*)d_in[6];
    const float* W_hh    = (const float*)d_in[7];
    const float* b_ih    = (const float*)d_in[8];
    const float* b_hh    = (const float*)d_in[9];
    const float* W_fc    = (const float*)d_in[10];
    const float* b_fc    = (const float*)d_in[11];
    float* out = (float*)d_out;

    const int N = NN;
    const int E = in_sizes[1] / 2;
    const int* src = ei;
    const int* dst = ei + E;

    // workspace layout
    char* w = (char*)d_ws;
    size_t off = 0;
    auto alloc = [&](size_t bytes) {
        char* p = w + off;
        off = (off + bytes + 255) & ~(size_t)255;
        return p;
    };
    int*   deg     = (int*)alloc((size_t)N * 4);
    int*   row_ptr = (int*)alloc((size_t)(N + 1) * 4);
    int*   cursor  = (int*)alloc((size_t)N * 4);
    int*   col     = (int*)alloc((size_t)(E + N) * 4);
    float* a_s     = (float*)alloc((size_t)N * 4);
    float* a_d     = (float*)alloc((size_t)N * 4);
    unsigned* xpb  = (unsigned*)alloc((size_t)N * 64 * 4);   // bf16 xp [N][128]
    float* spatial = (float*)alloc((size_t)N * HD * 4);
    float* hbuf    = (float*)alloc((size_t)N * HD * 4);
    short* wfrag   = (short*)alloc((size_t)3 * 4 * 8 * 4 * 64 * 8 * 2);  // 393KB

    // h0 = 0
    hipMemsetAsync(hbuf, 0, (size_t)N * HD * 4, stream);

    // CSR build + weight pack (once per launch)
    deg_init_kernel<<<(N + 255) / 256, 256, 0, stream>>>(deg, N);
    deg_count_kernel<<<(E + 255) / 256, 256, 0, stream>>>(dst, deg, E);
    scan_kernel<<<1, 1024, 0, stream>>>(deg, row_ptr, N);
    selfloop_kernel<<<(N + 255) / 256, 256, 0, stream>>>(row_ptr, cursor, col, N);
    scatter_kernel<<<(E + 255) / 256, 256, 0, stream>>>(src, dst, cursor, col, E);
    wpack_kernel<<<(24576 + 255) / 256, 256, 0, stream>>>(W_ih, W_hh, wfrag);

    int node_wave_blocks = (N * 64 + 255) / 256;  // one wave per node
    int gru_blocks = (N + 63) / 64;

    for (int t = 0; t < SEQ; ++t) {
        const float* xt = x_seq + (size_t)t * N * FIN;
        xp_kernel<<<node_wave_blocks, 256, 0, stream>>>(xt, Wg, att_src, att_dst,
                                                        xpb, a_s, a_d, N);
        gat_kernel<<<node_wave_blocks, 256, 0, stream>>>(row_ptr, col, a_s, a_d,
                                                         (const short*)xpb, bias_g,
                                                         spatial, N);
        gru_mfma_kernel<<<gru_blocks, 256, 0, stream>>>(spatial, hbuf, wfrag,
                                                        b_ih, b_hh, N);
    }
    fc_kernel<<<node_wave_blocks, 256, 0, stream>>>(hbuf, W_fc, b_fc, out, N);
}

// Round 7
// 6798.078 us; speedup vs baseline: 1.1974x; 1.1974x over previous
//
#include <hip/hip_runtime.h>
#include <math.h>

// Problem constants (match reference)
#define NN 50000
#define SEQ 52
#define FIN 16
#define HD 128
#define NEG_SLOPE 0.2f

typedef short bf16x8 __attribute__((ext_vector_type(8)));   // 8 bf16 (4 VGPRs)
typedef float f32x16 __attribute__((ext_vector_type(16)));  // 32x32 MFMA C/D

__device__ __forceinline__ short f2bf(float x) {
    unsigned u = __float_as_uint(x);
    u += 0x7fffu + ((u >> 16) & 1u);   // round-to-nearest-even
    return (short)(u >> 16);
}
__device__ __forceinline__ float b2f(short s) {
    return __uint_as_float(((unsigned)(unsigned short)s) << 16);
}

// ---------------------------------------------------------------------------
// CSR build kernels (run once per launch; graph is static across timesteps)
// ---------------------------------------------------------------------------
__global__ void deg_init_kernel(int* deg, int n) {
    int i = blockIdx.x * blockDim.x + threadIdx.x;
    if (i < n) deg[i] = 1;  // self-loop
}

__global__ void deg_count_kernel(const int* __restrict__ dst, int* deg, int e) {
    int i = blockIdx.x * blockDim.x + threadIdx.x;
    if (i < e) atomicAdd(&deg[dst[i]], 1);
}

__global__ __launch_bounds__(1024) void scan_kernel(const int* __restrict__ deg,
                                                    int* row_ptr, int n) {
    __shared__ int buf[1024];
    __shared__ int carry;
    int tid = threadIdx.x;
    if (tid == 0) carry = 0;
    __syncthreads();
    for (int base = 0; base < n; base += 1024) {
        int i = base + tid;
        int v = (i < n) ? deg[i] : 0;
        buf[tid] = v;
        __syncthreads();
        for (int off = 1; off < 1024; off <<= 1) {
            int t = (tid >= off) ? buf[tid - off] : 0;
            __syncthreads();
            buf[tid] += t;
            __syncthreads();
        }
        if (i < n) row_ptr[i] = carry + buf[tid] - v;  // exclusive
        __syncthreads();
        if (tid == 1023) carry += buf[1023];
        __syncthreads();
    }
    if (tid == 0) row_ptr[n] = carry;
}

__global__ void selfloop_kernel(const int* __restrict__ row_ptr, int* cursor,
                                int* col, int n) {
    int i = blockIdx.x * blockDim.x + threadIdx.x;
    if (i < n) {
        int p = row_ptr[i];
        col[p] = i;          // self-loop first
        cursor[i] = p + 1;
    }
}

__global__ void scatter_kernel(const int* __restrict__ src, const int* __restrict__ dst,
                               int* cursor, int* col, int e) {
    int i = blockIdx.x * blockDim.x + threadIdx.x;
    if (i < e) {
        int p = atomicAdd(&cursor[dst[i]], 1);
        col[p] = src[i];
    }
}

// ---------------------------------------------------------------------------
// Pack W_ih/W_hh into MFMA B-fragment order, split bf16 hi/lo.
// Index: ((((g*4+slab)*8+ks)*4+which)*64+lane)*8 shorts,
//   which: 0=ih_hi 1=ih_lo 2=hh_hi 3=hh_lo
//   col = slab*32 + (lane&31), kcol = ks*16 + (lane>>5)*8
// In the GRU K-loop every weight load is lane-contiguous 16B -> coalesced.
// ---------------------------------------------------------------------------
__global__ void wpack_kernel(const float* __restrict__ Wi, const float* __restrict__ Wh,
                             short* __restrict__ wfrag) {
    int idx = blockIdx.x * blockDim.x + threadIdx.x;
    if (idx >= 3 * 4 * 8 * 4 * 64) return;
    int lane = idx & 63;
    int which = (idx >> 6) & 3;
    int ks = (idx >> 8) & 7;
    int slab = (idx >> 11) & 3;
    int g = idx >> 13;
    int col = slab * 32 + (lane & 31);
    int kcol = ks * 16 + (lane >> 5) * 8;
    const float* Wsrc = (which < 2) ? Wi : Wh;
    const float* row = Wsrc + (size_t)(g * HD + col) * HD + kcol;
    short* dstp = wfrag + (size_t)idx * 8;
    bool lo = (which & 1);
#pragma unroll
    for (int e = 0; e < 8; ++e) {
        float v = row[e];
        short hi = f2bf(v);
        dstp[e] = lo ? f2bf(v - b2f(hi)) : hi;
    }
}

// ---------------------------------------------------------------------------
// Per-timestep kernels
// ---------------------------------------------------------------------------

// xp = x_t @ Wg (stored bf16); a_s = xp.att_src ; a_d = xp.att_dst (fp32 pre-round)
// One wave per node; lane handles features 2*lane, 2*lane+1 -> one packed u32 store.
__global__ __launch_bounds__(256) void xp_kernel(
    const float* __restrict__ x, const float* __restrict__ Wg,
    const float* __restrict__ att_src, const float* __restrict__ att_dst,
    unsigned* __restrict__ xpb, float* __restrict__ a_s, float* __restrict__ a_d, int n) {
    int wave = (blockIdx.x * blockDim.x + threadIdx.x) >> 6;
    int lane = threadIdx.x & 63;
    if (wave >= n) return;
    const float* xr = x + (size_t)wave * FIN;
    float xv[FIN];
#pragma unroll
    for (int k = 0; k < FIN; ++k) xv[k] = xr[k];
    int c0 = 2 * lane, c1 = 2 * lane + 1;
    float v0 = 0.f, v1 = 0.f;
#pragma unroll
    for (int k = 0; k < FIN; ++k) {
        v0 += xv[k] * Wg[k * HD + c0];
        v1 += xv[k] * Wg[k * HD + c1];
    }
    unsigned p = (unsigned)(unsigned short)f2bf(v0) |
                 ((unsigned)(unsigned short)f2bf(v1) << 16);
    xpb[(size_t)wave * 64 + lane] = p;
    float s = v0 * att_src[c0] + v1 * att_src[c1];
    float d = v0 * att_dst[c0] + v1 * att_dst[c1];
#pragma unroll
    for (int off = 32; off; off >>= 1) {
        s += __shfl_xor(s, off);
        d += __shfl_xor(d, off);
    }
    if (lane == 0) { a_s[wave] = s; a_d[wave] = d; }
}

// GAT softmax-aggregate: one wave per dst node, bf16 xp rows (256B/edge).
// Single pass (no max subtraction: scores ~N(0,0.64), exp() is safe).
// Lanes = 4 edge-groups x 16 feature-lanes; lane reads bf16x8 (16B) per edge.
__global__ __launch_bounds__(256) void gat_kernel(
    const int* __restrict__ row_ptr, const int* __restrict__ col,
    const float* __restrict__ a_s, const float* __restrict__ a_d,
    const short* __restrict__ xpb, const float* __restrict__ bias_g,
    float* __restrict__ spatial, int n) {
    int wave = (blockIdx.x * blockDim.x + threadIdx.x) >> 6;
    int lane = threadIdx.x & 63;
    if (wave >= n) return;
    int start = row_ptr[wave], end = row_ptr[wave + 1];
    int eg = lane >> 4;   // edge group 0..3
    int fg = lane & 15;   // feature lane 0..15 (features fg*8..fg*8+7)
    float ad = a_d[wave];
    float acc[8] = {0.f, 0.f, 0.f, 0.f, 0.f, 0.f, 0.f, 0.f};
    float denom = 0.f;
    for (int i = start + eg; i < end; i += 4) {
        int s = col[i];
        float e = a_s[s] + ad;
        e = (e > 0.f) ? e : NEG_SLOPE * e;
        float wgt = __expf(e);
        denom += wgt;
        bf16x8 row = *(const bf16x8*)(xpb + (size_t)s * HD + fg * 8);
#pragma unroll
        for (int j = 0; j < 8; ++j) acc[j] += wgt * b2f(row[j]);
    }
    // reduce across the 4 edge groups (lane bits 4,5)
    denom += __shfl_xor(denom, 16);
    denom += __shfl_xor(denom, 32);
#pragma unroll
    for (int j = 0; j < 8; ++j) {
        acc[j] += __shfl_xor(acc[j], 16);
        acc[j] += __shfl_xor(acc[j], 32);
    }
    float inv = 1.f / denom;
    // each lane writes 2 of its 8 features: f = fg*8 + eg*2 + jj
#pragma unroll
    for (int jj = 0; jj < 2; ++jj) {
        int f = fg * 8 + eg * 2 + jj;
        float o = acc[eg * 2 + jj] * inv + bias_g[f];
        spatial[(size_t)wave * HD + f] = fmaxf(o, 0.f);
    }
}

// ---------------------------------------------------------------------------
// MFMA GRU, 32-node tile, 4 accumulators, triple-buffered weight prefetch.
//   r/z gates: spatial@Wi_g and h@Wh_g accumulate into ONE C/D tile (only the
//   sum is ever used) -> 4 f32x16 accs (64 AGPR) instead of 6 (96).
//   n gate: separate i_n / h_n accs (r gates h_n).
//   split-bf16: A*W ~= Ah*Wh + Al*Wh + Ah*Wl (fp32 accumulate)
// Triple buffer: load ks+2 while MFMA-ing ks -> load->use distance ~340 cyc
// > L2 latency; 24 outstanding loads/wave. Regs ~144(w)+64(acc)+~40 <= 256
// -> 2 waves/SIMD enforced by launch_bounds(256,2).
// ---------------------------------------------------------------------------
__global__ __launch_bounds__(256, 2) void gru_mfma_kernel(
    const float* __restrict__ spatial, float* __restrict__ h,
    const short* __restrict__ wfrag,
    const float* __restrict__ b_ih, const float* __restrict__ b_hh, int n) {
    __shared__ bf16x8 sSH[512];  // spatial hi
    __shared__ bf16x8 sSL[512];  // spatial lo
    __shared__ bf16x8 sHH[512];  // h hi
    __shared__ bf16x8 sHL[512];  // h lo

    int t = threadIdx.x;
    int lane = t & 63;
    int w = t >> 6;
    int n0 = blockIdx.x * 32;

    // ---- stage: wave w converts k-steps 2w and 2w+1 into A-frag order ----
#pragma unroll
    for (int q = 0; q < 2; ++q) {
        int ks = w * 2 + q;
        int row = n0 + (lane & 31);
        if (row >= n) row = n - 1;
        int kcol = ks * 16 + (lane >> 5) * 8;
        const float* sp = spatial + (size_t)row * HD + kcol;
        const float* hp = h + (size_t)row * HD + kcol;
        float s8[8], h8[8];
        *(float4*)(s8) = *(const float4*)(sp);
        *(float4*)(s8 + 4) = *(const float4*)(sp + 4);
        *(float4*)(h8) = *(const float4*)(hp);
        *(float4*)(h8 + 4) = *(const float4*)(hp + 4);
        bf16x8 sh, sl, hh, hl;
#pragma unroll
        for (int j = 0; j < 8; ++j) {
            short a = f2bf(s8[j]);
            sh[j] = a;
            sl[j] = f2bf(s8[j] - b2f(a));
            short b = f2bf(h8[j]);
            hh[j] = b;
            hl[j] = f2bf(h8[j] - b2f(b));
        }
        int li = ks * 64 + lane;
        sSH[li] = sh; sSL[li] = sl; sHH[li] = hh; sHL[li] = hl;
    }
    __syncthreads();

    int j0 = w * 32;
    int cj = lane & 31;       // column within wave's 32-col slab
    int kh = lane >> 5;       // k-half for frags

    f32x16 arz[2], ain, ahn;  // r, z (merged i+h), i_n, h_n
#pragma unroll
    for (int r = 0; r < 16; ++r) {
        arz[0][r] = 0.f; arz[1][r] = 0.f; ain[r] = 0.f; ahn[r] = 0.f;
    }

    // fragment-ordered weight base for this wave: + g*65536 + ks*2048 + which*512
    const short* wb = wfrag + (size_t)w * 16384 + (size_t)lane * 8;

    // weight triple buffer: [buf][g*4 + which]
    bf16x8 wv[3][12];
#pragma unroll
    for (int p = 0; p < 2; ++p) {
#pragma unroll
        for (int g = 0; g < 3; ++g) {
#pragma unroll
            for (int q = 0; q < 4; ++q)
                wv[p][g * 4 + q] = *(const bf16x8*)(wb + g * 65536 + p * 2048 + q * 512);
        }
    }

#pragma unroll
    for (int ks = 0; ks < 8; ++ks) {
        int cur = ks % 3;
        if (ks < 6) {
            int nxt = (ks + 2) % 3;
#pragma unroll
            for (int g = 0; g < 3; ++g) {
#pragma unroll
                for (int q = 0; q < 4; ++q)
                    wv[nxt][g * 4 + q] =
                        *(const bf16x8*)(wb + g * 65536 + (ks + 2) * 2048 + q * 512);
            }
        }
        int li = ks * 64 + lane;
        bf16x8 aSH = sSH[li];
        bf16x8 aSL = sSL[li];
        bf16x8 aHH = sHH[li];
        bf16x8 aHL = sHL[li];
        // r and z gates: both GEMMs into one accumulator
#pragma unroll
        for (int g = 0; g < 2; ++g) {
            bf16x8 wih = wv[cur][g * 4 + 0];
            bf16x8 wil = wv[cur][g * 4 + 1];
            bf16x8 whh = wv[cur][g * 4 + 2];
            bf16x8 whl = wv[cur][g * 4 + 3];
            arz[g] = __builtin_amdgcn_mfma_f32_32x32x16_bf16(aSH, wih, arz[g], 0, 0, 0);
            arz[g] = __builtin_amdgcn_mfma_f32_32x32x16_bf16(aHH, whh, arz[g], 0, 0, 0);
            arz[g] = __builtin_amdgcn_mfma_f32_32x32x16_bf16(aSL, wih, arz[g], 0, 0, 0);
            arz[g] = __builtin_amdgcn_mfma_f32_32x32x16_bf16(aHL, whh, arz[g], 0, 0, 0);
            arz[g] = __builtin_amdgcn_mfma_f32_32x32x16_bf16(aSH, wil, arz[g], 0, 0, 0);
            arz[g] = __builtin_amdgcn_mfma_f32_32x32x16_bf16(aHH, whl, arz[g], 0, 0, 0);
        }
        // n gate: separate accs (r multiplies h_n before tanh)
        {
            bf16x8 wih = wv[cur][8];
            bf16x8 wil = wv[cur][9];
            bf16x8 whh = wv[cur][10];
            bf16x8 whl = wv[cur][11];
            ain = __builtin_amdgcn_mfma_f32_32x32x16_bf16(aSH, wih, ain, 0, 0, 0);
            ahn = __builtin_amdgcn_mfma_f32_32x32x16_bf16(aHH, whh, ahn, 0, 0, 0);
            ain = __builtin_amdgcn_mfma_f32_32x32x16_bf16(aSL, wih, ain, 0, 0, 0);
            ahn = __builtin_amdgcn_mfma_f32_32x32x16_bf16(aHL, whh, ahn, 0, 0, 0);
            ain = __builtin_amdgcn_mfma_f32_32x32x16_bf16(aSH, wil, ain, 0, 0, 0);
            ahn = __builtin_amdgcn_mfma_f32_32x32x16_bf16(aHH, whl, ahn, 0, 0, 0);
        }
    }

    // ---- wave-local GRU elementwise + h write ----
    int j = j0 + cj;
    float brz0 = b_ih[j] + b_hh[j];
    float brz1 = b_ih[HD + j] + b_hh[HD + j];
    float bin_ = b_ih[2 * HD + j];
    float bhn = b_hh[2 * HD + j];
    const short* hhs = (const short*)sHH;
    const short* hls = (const short*)sHL;
    int ksj = j >> 4, halfj = (j >> 3) & 1, ej = j & 7;

#pragma unroll
    for (int r = 0; r < 16; ++r) {
        int nl = (r & 3) + 8 * (r >> 2) + 4 * kh;  // C/D row mapping (m74/m101)
        int node = n0 + nl;
        if (node < n) {
            float rr = 1.f / (1.f + __expf(-(arz[0][r] + brz0)));
            float zz = 1.f / (1.f + __expf(-(arz[1][r] + brz1)));
            float nn2 = tanhf(ain[r] + bin_ + rr * (ahn[r] + bhn));
            int li = (ksj * 64 + nl + 32 * halfj) * 8 + ej;
            float hold = b2f(hhs[li]) + b2f(hls[li]);
            h[(size_t)node * HD + j] = (1.f - zz) * nn2 + zz * hold;
        }
    }
}

// out[n] = h[n] . W_fc + b_fc   (one wave per node)
__global__ __launch_bounds__(256) void fc_kernel(
    const float* __restrict__ h, const float* __restrict__ W_fc,
    const float* __restrict__ b_fc, float* __restrict__ out, int n) {
    int wave = (blockIdx.x * blockDim.x + threadIdx.x) >> 6;
    int lane = threadIdx.x & 63;
    if (wave >= n) return;
    float v = h[(size_t)wave * HD + lane] * W_fc[lane] +
              h[(size_t)wave * HD + lane + 64] * W_fc[lane + 64];
#pragma unroll
    for (int off = 32; off; off >>= 1) v += __shfl_xor(v, off);
    if (lane == 0) out[wave] = v + b_fc[0];
}

// ---------------------------------------------------------------------------
extern "C" void kernel_launch(void* const* d_in, const int* in_sizes, int n_in,
                              void* d_out, int out_size, void* d_ws, size_t ws_size,
                              hipStream_t stream) {
    const float* x_seq   = (const float*)d_in[0];
    const int*   ei      = (const int*)d_in[1];
    const float* Wg      = (const float*)d_in[2];
    const float* att_src = (const float*)d_in[3];
    const float* att_dst = (const float*)d_in[4];
    const float* bias_g  = (const float*)d_in[5];
    const float* W_ih    = (const float*)d_in[6];
    const float* W_hh    = (const float*)d_in[7];
    const float* b_ih    = (const float*)d_in[8];
    const float* b_hh    = (const float*)d_in[9];
    const float* W_fc    = (const float*)d_in[10];
    const float* b_fc    = (const float*)d_in[11];
    float* out = (float*)d_out;

    const int N = NN;
    const int E = in_sizes[1] / 2;
    const int* src = ei;
    const int* dst = ei + E;

    // workspace layout
    char* w = (char*)d_ws;
    size_t off = 0;
    auto alloc = [&](size_t bytes) {
        char* p = w + off;
        off = (off + bytes + 255) & ~(size_t)255;
        return p;
    };
    int*   deg     = (int*)alloc((size_t)N * 4);
    int*   row_ptr = (int*)alloc((size_t)(N + 1) * 4);
    int*   cursor  = (int*)alloc((size_t)N * 4);
    int*   col     = (int*)alloc((size_t)(E + N) * 4);
    float* a_s     = (float*)alloc((size_t)N * 4);
    float* a_d     = (float*)alloc((size_t)N * 4);
    unsigned* xpb  = (unsigned*)alloc((size_t)N * 64 * 4);   // bf16 xp [N][128]
    float* spatial = (float*)alloc((size_t)N * HD * 4);
    float* hbuf    = (float*)alloc((size_t)N * HD * 4);
    short* wfrag   = (short*)alloc((size_t)3 * 4 * 8 * 4 * 64 * 8 * 2);  // 393KB

    // h0 = 0
    hipMemsetAsync(hbuf, 0, (size_t)N * HD * 4, stream);

    // CSR build + weight pack (once per launch)
    deg_init_kernel<<<(N + 255) / 256, 256, 0, stream>>>(deg, N);
    deg_count_kernel<<<(E + 255) / 256, 256, 0, stream>>>(dst, deg, E);
    scan_kernel<<<1, 1024, 0, stream>>>(deg, row_ptr, N);
    selfloop_kernel<<<(N + 255) / 256, 256, 0, stream>>>(row_ptr, cursor, col, N);
    scatter_kernel<<<(E + 255) / 256, 256, 0, stream>>>(src, dst, cursor, col, E);
    wpack_kernel<<<(24576 + 255) / 256, 256, 0, stream>>>(W_ih, W_hh, wfrag);

    int node_wave_blocks = (N * 64 + 255) / 256;  // one wave per node
    int gru_blocks = (N + 31) / 32;

    for (int t = 0; t < SEQ; ++t) {
        const float* xt = x_seq + (size_t)t * N * FIN;
        xp_kernel<<<node_wave_blocks, 256, 0, stream>>>(xt, Wg, att_src, att_dst,
                                                        xpb, a_s, a_d, N);
        gat_kernel<<<node_wave_blocks, 256, 0, stream>>>(row_ptr, col, a_s, a_d,
                                                         (const short*)xpb, bias_g,
                                                         spatial, N);
        gru_mfma_kernel<<<gru_blocks, 256, 0, stream>>>(spatial, hbuf, wfrag,
                                                        b_ih, b_hh, N);
    }
    fc_kernel<<<node_wave_blocks, 256, 0, stream>>>(hbuf, W_fc, b_fc, out, N);
}